// Round 1
// baseline (4522.835 us; speedup 1.0000x reference)
//
#include <hip/hip_runtime.h>
#include <math.h>

#define THREADS 256

__device__ __forceinline__ float silu_f(float v) {
    return v / (1.f + __expf(-v));
}

// Direct conv2d, stride 1, pad (KS-1)/2, NCHW single image.
// One thread per output pixel, computes all COUT channels.
template<int CIN, int COUT, int KS, bool ACT>
__global__ __launch_bounds__(THREADS)
void conv_k(const float* __restrict__ in, const float* __restrict__ wgt,
            const float* __restrict__ bias, float* __restrict__ out,
            int H, int W)
{
    constexpr int PAD = (KS - 1) / 2;
    constexpr int NW = COUT * CIN * KS * KS;
    __shared__ float sw[NW];
    for (int i = threadIdx.x; i < NW; i += THREADS) sw[i] = wgt[i];
    __syncthreads();

    const int total = H * W;
    const int idx = blockIdx.x * THREADS + threadIdx.x;
    if (idx >= total) return;
    const int y = idx / W;
    const int x = idx - y * W;

    float acc[COUT];
#pragma unroll
    for (int co = 0; co < COUT; ++co) acc[co] = bias[co];

    for (int ci = 0; ci < CIN; ++ci) {
        const float* __restrict__ ip = in + ci * total;
#pragma unroll
        for (int ky = 0; ky < KS; ++ky) {
            const int yy = y + ky - PAD;
            if ((unsigned)yy >= (unsigned)H) continue;
#pragma unroll
            for (int kx = 0; kx < KS; ++kx) {
                const int xx = x + kx - PAD;
                if ((unsigned)xx >= (unsigned)W) continue;
                const float v = ip[yy * W + xx];
#pragma unroll
                for (int co = 0; co < COUT; ++co)
                    acc[co] = fmaf(v, sw[(co * CIN + ci) * (KS * KS) + ky * KS + kx], acc[co]);
            }
        }
    }

#pragma unroll
    for (int co = 0; co < COUT; ++co) {
        float r = acc[co];
        if (ACT) r = silu_f(r);
        out[co * total + idx] = r;
    }
}

// DeformConv2d: 3x3, stride 1, pad 1, dilation 1, no bias.
// groups = 2, offset groups = 2 (cpg == Cog, identical channel partition).
// offset layout: [OG=2][K=9][2(dy,dx)][H][W]
template<int CIN, int COUT>
__global__ __launch_bounds__(THREADS)
void dconv_k(const float* __restrict__ in, const float* __restrict__ off,
             const float* __restrict__ wgt, float* __restrict__ out,
             int H, int W)
{
    constexpr int K = 9;
    constexpr int OG = 2;
    constexpr int COG = CIN / OG;      // input chans per offset group
    constexpr int CPG = CIN / 2;       // input chans per conv group (== COG)
    constexpr int COUTG = COUT / 2;    // output chans per conv group
    constexpr int NW = COUT * CPG * K;
    __shared__ float sw[NW];
    for (int i = threadIdx.x; i < NW; i += THREADS) sw[i] = wgt[i];
    __syncthreads();

    const int total = H * W;
    const int idx = blockIdx.x * THREADS + threadIdx.x;
    if (idx >= total) return;
    const int y = idx / W;
    const int x = idx - y * W;

    float acc[COUT];
#pragma unroll
    for (int co = 0; co < COUT; ++co) acc[co] = 0.f;

#pragma unroll
    for (int og = 0; og < OG; ++og) {
#pragma unroll
        for (int k = 0; k < K; ++k) {
            const int ki = k / 3 - 1;
            const int kj = k % 3 - 1;
            const float dy = off[((og * K + k) * 2 + 0) * total + idx];
            const float dx = off[((og * K + k) * 2 + 1) * total + idx];
            const float py = dy + (float)(y + ki);
            const float px = dx + (float)(x + kj);
            const float y0f = floorf(py), x0f = floorf(px);
            const float ly = py - y0f, lx = px - x0f;
            const int y0 = (int)y0f, x0 = (int)x0f;
            const int y1 = y0 + 1, x1 = x0 + 1;
            const bool vy0 = (unsigned)y0 < (unsigned)H;
            const bool vy1 = (unsigned)y1 < (unsigned)H;
            const bool vx0 = (unsigned)x0 < (unsigned)W;
            const bool vx1 = (unsigned)x1 < (unsigned)W;
            // clamped gather indices (always in-bounds address), weight zeroed if invalid
            const int cy0 = min(max(y0, 0), H - 1), cy1 = min(max(y1, 0), H - 1);
            const int cx0 = min(max(x0, 0), W - 1), cx1 = min(max(x1, 0), W - 1);
            const int i00 = cy0 * W + cx0, i01 = cy0 * W + cx1;
            const int i10 = cy1 * W + cx0, i11 = cy1 * W + cx1;
            const float f00 = (vy0 && vx0) ? (1.f - ly) * (1.f - lx) : 0.f;
            const float f01 = (vy0 && vx1) ? (1.f - ly) * lx : 0.f;
            const float f10 = (vy1 && vx0) ? ly * (1.f - lx) : 0.f;
            const float f11 = (vy1 && vx1) ? ly * lx : 0.f;
#pragma unroll
            for (int c = 0; c < COG; ++c) {
                const float* __restrict__ ip = in + (og * COG + c) * total;
                const float v = f00 * ip[i00] + f01 * ip[i01]
                              + f10 * ip[i10] + f11 * ip[i11];
#pragma unroll
                for (int cl = 0; cl < COUTG; ++cl) {
                    const int co = og * COUTG + cl;
                    acc[co] = fmaf(v, sw[(co * CPG + c) * K + k], acc[co]);
                }
            }
        }
    }

#pragma unroll
    for (int co = 0; co < COUT; ++co)
        out[co * total + idx] = acc[co];
}

// 2x2 average pool; H,W are INPUT dims.
__global__ __launch_bounds__(THREADS)
void avgpool_k(const float* __restrict__ in, float* __restrict__ out,
               int C, int H, int W)
{
    const int Ho = H >> 1, Wo = W >> 1;
    const int n = C * Ho * Wo;
    const int idx = blockIdx.x * THREADS + threadIdx.x;
    if (idx >= n) return;
    const int c = idx / (Ho * Wo);
    const int r = idx - c * (Ho * Wo);
    const int oy = r / Wo, ox = r - oy * Wo;
    const float* ip = in + c * H * W + (2 * oy) * W + 2 * ox;
    out[idx] = 0.25f * (ip[0] + ip[1] + ip[W] + ip[W + 1]);
}

// Bilinear 2x upsample, align_corners=True; H,W are INPUT dims.
__global__ __launch_bounds__(THREADS)
void up2x_k(const float* __restrict__ in, float* __restrict__ out,
            int C, int H, int W)
{
    const int Ho = 2 * H, Wo = 2 * W;
    const int n = C * Ho * Wo;
    const int idx = blockIdx.x * THREADS + threadIdx.x;
    if (idx >= n) return;
    const int c = idx / (Ho * Wo);
    const int r = idx - c * (Ho * Wo);
    const int oy = r / Wo, ox = r - oy * Wo;
    const float sy = (float)(H - 1) / (float)(Ho - 1);
    const float sx = (float)(W - 1) / (float)(Wo - 1);
    const float fy = (float)oy * sy;
    const float fx = (float)ox * sx;
    const int y0 = (int)floorf(fy);
    const int x0 = (int)floorf(fx);
    const int y1 = min(y0 + 1, H - 1);
    const int x1 = min(x0 + 1, W - 1);
    const float wy = fy - (float)y0;
    const float wx = fx - (float)x0;
    const float* ip = in + c * H * W;
    const float v = (ip[y0 * W + x0] * (1.f - wy) + ip[y1 * W + x0] * wy) * (1.f - wx)
                  + (ip[y0 * W + x1] * (1.f - wy) + ip[y1 * W + x1] * wy) * wx;
    out[idx] = v;
}

extern "C" void kernel_launch(void* const* d_in, const int* in_sizes, int n_in,
                              void* d_out, int out_size, void* d_ws, size_t ws_size,
                              hipStream_t stream) {
    const float* x      = (const float*)d_in[0];
    const float* eo1_w1 = (const float*)d_in[1];
    const float* eo1_b1 = (const float*)d_in[2];
    const float* eo1_w2 = (const float*)d_in[3];
    const float* eo1_b2 = (const float*)d_in[4];
    const float* dcw1   = (const float*)d_in[5];
    const float* c1d_w1 = (const float*)d_in[6];
    const float* c1d_b1 = (const float*)d_in[7];
    const float* c1d_w2 = (const float*)d_in[8];
    const float* c1d_b2 = (const float*)d_in[9];
    const float* eo2_w1 = (const float*)d_in[10];
    const float* eo2_b1 = (const float*)d_in[11];
    const float* eo2_w2 = (const float*)d_in[12];
    const float* eo2_b2 = (const float*)d_in[13];
    const float* dcw2   = (const float*)d_in[14];
    const float* c2d_w1 = (const float*)d_in[15];
    const float* c2d_b1 = (const float*)d_in[16];
    const float* c2d_w2 = (const float*)d_in[17];
    const float* c2d_b2 = (const float*)d_in[18];
    const float* eo3_w1 = (const float*)d_in[19];
    const float* eo3_b1 = (const float*)d_in[20];
    const float* eo3_w2 = (const float*)d_in[21];
    const float* eo3_b2 = (const float*)d_in[22];
    const float* dcw3   = (const float*)d_in[23];
    const float* c3d_w1 = (const float*)d_in[24];
    const float* c3d_b1 = (const float*)d_in[25];
    const float* c3d_w2 = (const float*)d_in[26];
    const float* c3d_b2 = (const float*)d_in[27];
    const float* up2_w  = (const float*)d_in[28];
    const float* up2_b  = (const float*)d_in[29];
    const float* c2u_w1 = (const float*)d_in[30];
    const float* c2u_b1 = (const float*)d_in[31];
    const float* c2u_w2 = (const float*)d_in[32];
    const float* c2u_b2 = (const float*)d_in[33];
    const float* up1_w  = (const float*)d_in[34];
    const float* up1_b  = (const float*)d_in[35];
    const float* c1u_w1 = (const float*)d_in[36];
    const float* c1u_b1 = (const float*)d_in[37];
    const float* c1u_w2 = (const float*)d_in[38];
    const float* c1u_b2 = (const float*)d_in[39];

    float* out = (float*)d_out;
    float* ws  = (float*)d_ws;

    constexpr int H1 = 512, W1 = 512, A1 = H1 * W1;
    constexpr int H2 = 256, W2 = 256, A2 = H2 * W2;
    constexpr int H3 = 128, W3 = 128, A3 = H3 * W3;

    // per-batch workspace slots (total ~79.7 MB of floats)
    float* S0 = ws;                 // 36*A1
    float* S1 = S0 + 36 * A1;       // 18*A1
    float* S2 = S1 + 18 * A1;       //  8*A1
    float* P  = S2 + 8 * A1;        //  8*A2
    float* L1 = P + 8 * A2;         //  8*A1  (conv1_d skip)
    float* L2 = L1 + 8 * A1;        // 16*A2  (conv2_d skip)

    auto grid = [](int n) { return (n + THREADS - 1) / THREADS; };

    for (int b = 0; b < 4; ++b) {
        const float* xb = x + b * 4 * A1;
        float* outb = out + b * 2 * A1;

        // ---- level 1 down ----
        conv_k<4, 18, 5, false><<<grid(A1), THREADS, 0, stream>>>(xb, eo1_w1, eo1_b1, S1, H1, W1);
        conv_k<18, 36, 5, false><<<grid(A1), THREADS, 0, stream>>>(S1, eo1_w2, eo1_b2, S0, H1, W1);
        dconv_k<4, 2><<<grid(A1), THREADS, 0, stream>>>(xb, S0, dcw1, S2, H1, W1);
        conv_k<2, 4, 3, true><<<grid(A1), THREADS, 0, stream>>>(S2, c1d_w1, c1d_b1, S1, H1, W1);
        conv_k<4, 8, 3, true><<<grid(A1), THREADS, 0, stream>>>(S1, c1d_w2, c1d_b2, L1, H1, W1);
        avgpool_k<<<grid(8 * A2), THREADS, 0, stream>>>(L1, P, 8, H1, W1);

        // ---- level 2 down ----
        conv_k<8, 18, 5, false><<<grid(A2), THREADS, 0, stream>>>(P, eo2_w1, eo2_b1, S1, H2, W2);
        conv_k<18, 36, 5, false><<<grid(A2), THREADS, 0, stream>>>(S1, eo2_w2, eo2_b2, S0, H2, W2);
        dconv_k<8, 8><<<grid(A2), THREADS, 0, stream>>>(P, S0, dcw2, S2, H2, W2);
        conv_k<8, 12, 3, true><<<grid(A2), THREADS, 0, stream>>>(S2, c2d_w1, c2d_b1, S1, H2, W2);
        conv_k<12, 16, 3, true><<<grid(A2), THREADS, 0, stream>>>(S1, c2d_w2, c2d_b2, L2, H2, W2);
        avgpool_k<<<grid(16 * A3), THREADS, 0, stream>>>(L2, P, 16, H2, W2);

        // ---- level 3 (bottleneck) ----
        conv_k<16, 18, 5, false><<<grid(A3), THREADS, 0, stream>>>(P, eo3_w1, eo3_b1, S1, H3, W3);
        conv_k<18, 36, 5, false><<<grid(A3), THREADS, 0, stream>>>(S1, eo3_w2, eo3_b2, S0, H3, W3);
        dconv_k<16, 16><<<grid(A3), THREADS, 0, stream>>>(P, S0, dcw3, S2, H3, W3);
        conv_k<16, 14, 3, true><<<grid(A3), THREADS, 0, stream>>>(S2, c3d_w1, c3d_b1, S1, H3, W3);
        conv_k<14, 12, 3, true><<<grid(A3), THREADS, 0, stream>>>(S1, c3d_w2, c3d_b2, S2, H3, W3);

        // ---- up path level 2 ----
        up2x_k<<<grid(12 * A2), THREADS, 0, stream>>>(S2, S0, 12, H3, W3);
        conv_k<12, 12, 3, true><<<grid(A2), THREADS, 0, stream>>>(S0, up2_w, up2_b, S1, H2, W2); // cat2[0:12)
        hipMemcpyAsync(S1 + 12 * A2, L2, (size_t)16 * A2 * sizeof(float),
                       hipMemcpyDeviceToDevice, stream);                                          // cat2[12:28)
        conv_k<28, 16, 3, true><<<grid(A2), THREADS, 0, stream>>>(S1, c2u_w1, c2u_b1, S0, H2, W2);
        conv_k<16, 8, 3, true><<<grid(A2), THREADS, 0, stream>>>(S0, c2u_w2, c2u_b2, S2, H2, W2);

        // ---- up path level 1 ----
        up2x_k<<<grid(8 * A1), THREADS, 0, stream>>>(S2, S0, 8, H2, W2);
        conv_k<8, 8, 3, true><<<grid(A1), THREADS, 0, stream>>>(S0, up1_w, up1_b, S1, H1, W1);   // cat1[0:8)
        hipMemcpyAsync(S1 + 8 * A1, L1, (size_t)8 * A1 * sizeof(float),
                       hipMemcpyDeviceToDevice, stream);                                          // cat1[8:16)
        conv_k<16, 8, 3, true><<<grid(A1), THREADS, 0, stream>>>(S1, c1u_w1, c1u_b1, S0, H1, W1);
        conv_k<8, 2, 3, true><<<grid(A1), THREADS, 0, stream>>>(S0, c1u_w2, c1u_b2, outb, H1, W1);
    }
}